// Round 1
// baseline (1254.942 us; speedup 1.0000x reference)
//
#include <hip/hip_runtime.h>

// RandomHingeForest forward
// x:          [8192, 1024]  f32
// thresholds: [1024, 1023]  f32   (heap layout, children 2i+1 / 2i+2)
// ordinals:   [1024, 1023]  i32
// weights:    [1024, 1024, 16] f32
// out:        [8192, 1024, 16] f32 = min|x[ord]-thr| along path * leaf weights

#define BATCH    8192
#define IN_CH    1024
#define TREES    1024
#define N_NODES  1023
#define N_LEAVES 1024
#define DEPTH    10
#define EXTRA    16
#define TPB      256

__global__ __launch_bounds__(TPB, 8) void hinge_forest_kernel(
    const float* __restrict__ x,
    const float* __restrict__ thr,
    const int*   __restrict__ ord,
    const float* __restrict__ w,
    float*       __restrict__ out) {
  __shared__ float xrow[IN_CH];

  const int b = blockIdx.y;                       // batch sample for this block
  const int t = blockIdx.x * TPB + threadIdx.x;   // tree for this thread

  // Stage x[b, :] (4 KiB) into LDS: 256 threads x float4, fully coalesced.
  reinterpret_cast<float4*>(xrow)[threadIdx.x] =
      reinterpret_cast<const float4*>(x + (size_t)b * IN_CH)[threadIdx.x];
  __syncthreads();

  const float* tthr = thr + (size_t)t * N_NODES;
  const int*   tord = ord + (size_t)t * N_NODES;

  int   node = 0;
  float mm   = INFINITY;
#pragma unroll
  for (int d = 0; d < DEPTH; ++d) {
    const float th = tthr[node];
    const int   o  = tord[node];
    const float m  = xrow[o] - th;
    mm   = fminf(mm, fabsf(m));
    node = 2 * node + 1 + (m > 0.0f);             // strict >, matches reference
  }
  const int leaf = node - N_NODES;                // in [0, 1024)

  // out[b, t, :] = mm * weights[t, leaf, :]  (64 B gather, 64 B store)
  const float4* wp = reinterpret_cast<const float4*>(
      w + ((size_t)t * N_LEAVES + leaf) * EXTRA);
  float4* op = reinterpret_cast<float4*>(
      out + ((size_t)b * TREES + t) * EXTRA);
#pragma unroll
  for (int e = 0; e < 4; ++e) {
    const float4 wv = wp[e];
    op[e] = make_float4(mm * wv.x, mm * wv.y, mm * wv.z, mm * wv.w);
  }
}

extern "C" void kernel_launch(void* const* d_in, const int* in_sizes, int n_in,
                              void* d_out, int out_size, void* d_ws, size_t ws_size,
                              hipStream_t stream) {
  const float* x   = (const float*)d_in[0];
  const float* thr = (const float*)d_in[1];
  const int*   ord = (const int*)d_in[2];
  const float* w   = (const float*)d_in[3];
  float*       out = (float*)d_out;

  dim3 grid(TREES / TPB, BATCH);
  hinge_forest_kernel<<<grid, dim3(TPB, 1, 1), 0, stream>>>(x, thr, ord, w, out);
}

// Round 5
// 866.513 us; speedup vs baseline: 1.4483x; 1.4483x over previous
//
#include <hip/hip_runtime.h>

// RandomHingeForest forward
// x:          [8192, 1024]  f32
// thresholds: [1024, 1023]  f32   (heap layout, children 2i+1 / 2i+2)
// ordinals:   [1024, 1023]  i32
// weights:    [1024, 1024, 16] f32
// out:        [8192, 1024, 16] f32 = min|x[ord]-thr| along path * leaf weights
//
// Key layout trick: packed node-major records pk[node][tree] = {thr, ord}
// (float2, built in d_ws each launch). Wave lanes = consecutive trees, so
// shallow levels of the walk coalesce (all lanes at node 0 -> 8 lines not 64),
// and packing halves the scattered-transaction count at deep levels.

#define BATCH    8192
#define IN_CH    1024
#define TREES    1024
#define N_NODES  1023
#define N_LEAVES 1024
#define DEPTH    10
#define EXTRA    16
#define TPB      256
#define BPB      2          // batch samples (chains) per thread

// ---------------- prep: pk[n][t] = {thr[t][n], bits(ord[t][n])} -------------
__global__ __launch_bounds__(TPB) void pack_nodes_kernel(
    const float* __restrict__ thr, const int* __restrict__ ord,
    float2* __restrict__ pk) {
  int i = blockIdx.x * TPB + threadIdx.x;          // i = n*TREES + t
  if (i >= TREES * N_NODES) return;
  int n = i / TREES;
  int t = i - n * TREES;
  pk[i] = make_float2(thr[(size_t)t * N_NODES + n],
                      __int_as_float(ord[(size_t)t * N_NODES + n]));
}

// ---------------- main walk: 2 samples x 1 tree per thread ------------------
__global__ __launch_bounds__(TPB, 8) void hinge_forest_kernel(
    const float* __restrict__ x,
    const float2* __restrict__ pk,
    const float* __restrict__ w,
    float*       __restrict__ out) {
  __shared__ float xrow[BPB][IN_CH];

  const int b0 = blockIdx.y * BPB;
  const int t  = blockIdx.x * TPB + threadIdx.x;

  // Stage BPB x-rows (4 KiB each) into LDS, coalesced float4.
#pragma unroll
  for (int r = 0; r < BPB; ++r) {
    reinterpret_cast<float4*>(xrow[r])[threadIdx.x] =
        reinterpret_cast<const float4*>(x + (size_t)(b0 + r) * IN_CH)[threadIdx.x];
  }
  __syncthreads();

  int   n0 = 0, n1 = 0;
  float m0 = INFINITY, m1 = INFINITY;
#pragma unroll
  for (int d = 0; d < DEPTH; ++d) {
    // two independent 8 B gathers -> 2-deep MLP per thread
    const float2 a0 = pk[(size_t)n0 * TREES + t];
    const float2 a1 = pk[(size_t)n1 * TREES + t];
    const float g0 = xrow[0][__float_as_int(a0.y)] - a0.x;
    const float g1 = xrow[1][__float_as_int(a1.y)] - a1.x;
    m0 = fminf(m0, fabsf(g0));
    m1 = fminf(m1, fabsf(g1));
    n0 = 2 * n0 + 1 + (g0 > 0.0f);
    n1 = 2 * n1 + 1 + (g1 > 0.0f);
  }
  const int l0 = n0 - N_NODES;
  const int l1 = n1 - N_NODES;

  const float4* w0 = reinterpret_cast<const float4*>(
      w + ((size_t)t * N_LEAVES + l0) * EXTRA);
  const float4* w1 = reinterpret_cast<const float4*>(
      w + ((size_t)t * N_LEAVES + l1) * EXTRA);
  float4* o0 = reinterpret_cast<float4*>(
      out + ((size_t)b0 * TREES + t) * EXTRA);
  float4* o1 = reinterpret_cast<float4*>(
      out + ((size_t)(b0 + 1) * TREES + t) * EXTRA);
#pragma unroll
  for (int e = 0; e < 4; ++e) {
    const float4 wv0 = w0[e];
    const float4 wv1 = w1[e];
    o0[e] = make_float4(m0 * wv0.x, m0 * wv0.y, m0 * wv0.z, m0 * wv0.w);
    o1[e] = make_float4(m1 * wv1.x, m1 * wv1.y, m1 * wv1.z, m1 * wv1.w);
  }
}

// ---------------- fallback (ws too small): direct thr/ord reads -------------
__global__ __launch_bounds__(TPB, 8) void hinge_forest_fallback(
    const float* __restrict__ x,
    const float* __restrict__ thr,
    const int*   __restrict__ ord,
    const float* __restrict__ w,
    float*       __restrict__ out) {
  __shared__ float xrow[IN_CH];
  const int b = blockIdx.y;
  const int t = blockIdx.x * TPB + threadIdx.x;
  reinterpret_cast<float4*>(xrow)[threadIdx.x] =
      reinterpret_cast<const float4*>(x + (size_t)b * IN_CH)[threadIdx.x];
  __syncthreads();
  const float* tthr = thr + (size_t)t * N_NODES;
  const int*   tord = ord + (size_t)t * N_NODES;
  int node = 0; float mm = INFINITY;
#pragma unroll
  for (int d = 0; d < DEPTH; ++d) {
    const float th = tthr[node];
    const int   o  = tord[node];
    const float m  = xrow[o] - th;
    mm = fminf(mm, fabsf(m));
    node = 2 * node + 1 + (m > 0.0f);
  }
  const int leaf = node - N_NODES;
  const float4* wp = reinterpret_cast<const float4*>(
      w + ((size_t)t * N_LEAVES + leaf) * EXTRA);
  float4* op = reinterpret_cast<float4*>(
      out + ((size_t)b * TREES + t) * EXTRA);
#pragma unroll
  for (int e = 0; e < 4; ++e) {
    const float4 wv = wp[e];
    op[e] = make_float4(mm * wv.x, mm * wv.y, mm * wv.z, mm * wv.w);
  }
}

extern "C" void kernel_launch(void* const* d_in, const int* in_sizes, int n_in,
                              void* d_out, int out_size, void* d_ws, size_t ws_size,
                              hipStream_t stream) {
  const float* x   = (const float*)d_in[0];
  const float* thr = (const float*)d_in[1];
  const int*   ord = (const int*)d_in[2];
  const float* w   = (const float*)d_in[3];
  float*       out = (float*)d_out;

  const size_t pk_bytes = (size_t)TREES * N_NODES * sizeof(float2);  // 8 MiB
  if (ws_size >= pk_bytes) {
    float2* pk = (float2*)d_ws;
    const int total = TREES * N_NODES;
    pack_nodes_kernel<<<(total + TPB - 1) / TPB, TPB, 0, stream>>>(thr, ord, pk);
    dim3 grid(TREES / TPB, BATCH / BPB);
    hinge_forest_kernel<<<grid, dim3(TPB, 1, 1), 0, stream>>>(x, pk, w, out);
  } else {
    dim3 grid(TREES / TPB, BATCH);
    hinge_forest_fallback<<<grid, dim3(TPB, 1, 1), 0, stream>>>(x, thr, ord, w, out);
  }
}